// Round 3
// baseline (113.702 us; speedup 1.0000x reference)
//
#include <hip/hip_runtime.h>
#include <hip/hip_bf16.h>

// Problem constants
#define B_   2
#define CH   32      // C
#define S_   1024    // H*W
#define DM   64      // D_MODEL
#define NH   4       // N_HEADS
#define DH   16      // D_HEAD
#define COUT 64
#define NJ   4       // j-split factor
#define L2E  1.44269504088896f

// ws layout (floats):
//   [0..3]            a[h]       = (qv.kv)|head_h / sqrt(DH)
//   [16..271]         ov[o*4+h]  = sum_{d in head h} o_w[o,d]*vv[d]
//   [512 .. 66047]    t_all[b][c][s]  (2*32*1024 transposed x)
//   [66048 ..]        num[n][h][jc][s]  (64*4*4*1024 = 1048576 floats)
//   [+1048576]        den[n][h][jc][s]
#define WS_A   0
#define WS_OV  16
#define WS_T   512
#define WS_P   66048
#define PSZ    1048576

#if __has_builtin(__builtin_amdgcn_exp2f)
#define EXP2F(x) __builtin_amdgcn_exp2f(x)
#else
#define EXP2F(x) exp2f(x)
#endif

// ---------------------------------------------------------------------------
// Transpose x[b][s][c] -> t_all[b][c][s] so k_attn can stage coalesced.
__global__ __launch_bounds__(256) void k_tr(const float* __restrict__ x,
                                            float* __restrict__ ws) {
    __shared__ float tile[32][33];
    const int b  = blockIdx.x >> 5;
    const int s0 = (blockIdx.x & 31) * 32;
    const int tid = threadIdx.x;
    const int c = tid & 31, r = tid >> 5;     // 8 rows per pass
    #pragma unroll
    for (int k = 0; k < 4; k++)
        tile[r + 8 * k][c] = x[(b * S_ + s0 + r + 8 * k) * CH + c];
    __syncthreads();
    const int sl = tid & 31, cr = tid >> 5;
    #pragma unroll
    for (int k = 0; k < 4; k++) {
        int c2 = cr + 8 * k;
        ws[WS_T + (b * CH + c2) * S_ + s0 + sl] = tile[sl][c2];
    }
}

// ---------------------------------------------------------------------------
// Tiny prep: a[4] and ov[64][4].
__global__ __launch_bounds__(256) void k_prep(const float* __restrict__ embed_w,
                                              const float* __restrict__ q_w,
                                              const float* __restrict__ k_w,
                                              const float* __restrict__ v_w,
                                              const float* __restrict__ o_w,
                                              float* __restrict__ ws) {
    __shared__ float em[DM], qv[DM], kv[DM], vv[DM];
    __shared__ float qp[256], kp[256], vp[256];
    const int tid = threadIdx.x;
    if (tid < DM) em[tid] = embed_w[tid];
    __syncthreads();
    const int d = tid & 63, p = tid >> 6;
    float sq = 0.f, sk = 0.f, sv = 0.f;
    #pragma unroll
    for (int i = 0; i < 16; i++) {
        int e = p * 16 + i;
        float emv = em[e];
        sq = fmaf(q_w[d * DM + e], emv, sq);
        sk = fmaf(k_w[d * DM + e], emv, sk);
        sv = fmaf(v_w[d * DM + e], emv, sv);
    }
    qp[tid] = sq; kp[tid] = sk; vp[tid] = sv;
    __syncthreads();
    if (tid < DM) {
        qv[tid] = ((qp[tid] + qp[64 + tid]) + (qp[128 + tid] + qp[192 + tid]));
        kv[tid] = ((kp[tid] + kp[64 + tid]) + (kp[128 + tid] + kp[192 + tid]));
        vv[tid] = ((vp[tid] + vp[64 + tid]) + (vp[128 + tid] + vp[192 + tid]));
    }
    __syncthreads();
    if (tid < NH) {
        float a = 0.f;
        #pragma unroll
        for (int i = 0; i < DH; i++) a = fmaf(qv[tid * DH + i], kv[tid * DH + i], a);
        ws[WS_A + tid] = a * 0.25f;   // 1/sqrt(16)
    }
    const int o = tid & 63, h = tid >> 6;
    float s = 0.f;
    #pragma unroll
    for (int i = 0; i < DH; i++)
        s = fmaf(o_w[o * DM + h * DH + i], vv[h * DH + i], s);
    ws[WS_OV + o * NH + h] = s;
}

// ---------------------------------------------------------------------------
// Main: grid = 64 n * 4 schunk * 4 jchunk.  256 threads = 4 h * 64 s-quads.
// Each thread: 4 s-values, 256 j-values -> partial num/den.
__global__ __launch_bounds__(256) void k_attn(const float* __restrict__ ws_t,
                                              const float* __restrict__ ws_a,
                                              float* __restrict__ pnum,
                                              float* __restrict__ pden) {
    __shared__ __align__(16) float t[S_];
    __shared__ float redmax[4], redmin[4];
    const int bx  = blockIdx.x;
    const int n   = bx >> 4;
    const int sch = (bx >> 2) & 3;
    const int jc  = bx & 3;
    const int tid = threadIdx.x;

    // coalesced stage of this channel's t row (4 KB)
    float4 v = ((const float4*)(ws_t + n * S_))[tid];
    ((float4*)t)[tid] = v;
    float lmax = fmaxf(fmaxf(v.x, v.y), fmaxf(v.z, v.w));
    float lmin = fminf(fminf(v.x, v.y), fminf(v.z, v.w));
    #pragma unroll
    for (int off = 32; off; off >>= 1) {
        lmax = fmaxf(lmax, __shfl_xor(lmax, off));
        lmin = fminf(lmin, __shfl_xor(lmin, off));
    }
    if ((tid & 63) == 0) { redmax[tid >> 6] = lmax; redmin[tid >> 6] = lmin; }
    __syncthreads();
    const float tmax = fmaxf(fmaxf(redmax[0], redmax[1]), fmaxf(redmax[2], redmax[3]));
    const float tmin = fminf(fminf(redmin[0], redmin[1]), fminf(redmin[2], redmin[3]));

    const int h  = tid >> 6;
    const int sq = tid & 63;
    const float a = ws_a[h];

    const float4 ts = ((const float4*)t)[sch * 64 + sq];
    float cc2[4], nm2[4], an[4], ad[4];
    const float tsv[4] = {ts.x, ts.y, ts.z, ts.w};
    #pragma unroll
    for (int i = 0; i < 4; i++) {
        float cc = tsv[i] * a;
        cc2[i] = cc * L2E;
        nm2[i] = -fmaxf(cc * tmax, cc * tmin) * L2E;   // exact logit max
        an[i] = 0.f; ad[i] = 0.f;
    }

    const float4* tj4 = ((const float4*)t) + jc * 64;
    #pragma unroll 2
    for (int jq = 0; jq < 64; jq++) {
        float4 tj = tj4[jq];                 // broadcast (same addr all lanes)
        const float tjv[4] = {tj.x, tj.y, tj.z, tj.w};
        #pragma unroll
        for (int k = 0; k < 4; k++) {
            #pragma unroll
            for (int i = 0; i < 4; i++) {
                float e = EXP2F(fmaf(cc2[i], tjv[k], nm2[i]));
                an[i] = fmaf(e, tjv[k], an[i]);
                ad[i] += e;
            }
        }
    }

    const int base = (((n * NH + h) * NJ + jc) << 10) + sch * 256 + sq * 4;
    *(float4*)(pnum + base) = make_float4(an[0], an[1], an[2], an[3]);
    *(float4*)(pden + base) = make_float4(ad[0], ad[1], ad[2], ad[3]);
}

// ---------------------------------------------------------------------------
// Epilogue: combine j-partials, divide, weight by merge_w over c, project ov.
// grid = 2 b * 64 s-tiles(16).  256 threads.
__global__ __launch_bounds__(256) void k_fin(const float* __restrict__ ws,
                                             const float* __restrict__ merge_w,
                                             float* __restrict__ out) {
    __shared__ float part[4][4][16];   // [cgroup][h][s_l]
    __shared__ float W2[4][16];
    __shared__ float ovs[256];
    __shared__ float msh[32];
    const int b  = blockIdx.x >> 6;
    const int s0 = (blockIdx.x & 63) * 16;
    const int tid = threadIdx.x;
    ovs[tid] = ws[WS_OV + tid];
    if (tid < 32) msh[tid] = merge_w[tid];
    __syncthreads();

    const int sl = tid & 15, h = (tid >> 4) & 3, cg = tid >> 6;
    const float* pnum = ws + WS_P;
    const float* pden = ws + WS_P + PSZ;
    float acc = 0.f;
    #pragma unroll
    for (int k = 0; k < 8; k++) {
        int c = cg * 8 + k;
        int base = (((b * CH + c) * NH + h) * NJ) * S_ + s0 + sl;
        float ns = ((pnum[base] + pnum[base + 1024]) +
                    (pnum[base + 2048] + pnum[base + 3072]));
        float ds = ((pden[base] + pden[base + 1024]) +
                    (pden[base + 2048] + pden[base + 3072]));
        acc = fmaf(msh[c], ns * __builtin_amdgcn_rcpf(ds), acc);
    }
    part[cg][h][sl] = acc;
    __syncthreads();
    if (tid < 64) {
        int hh = tid >> 4, ss = tid & 15;
        W2[hh][ss] = ((part[0][hh][ss] + part[1][hh][ss]) +
                      (part[2][hh][ss] + part[3][hh][ss]));
    }
    __syncthreads();
    #pragma unroll
    for (int rep = 0; rep < 4; rep++) {
        int idx = rep * 256 + tid;
        int o = idx & 63, ss = idx >> 6;
        float r = 0.f;
        #pragma unroll
        for (int hh = 0; hh < NH; hh++)
            r = fmaf(ovs[o * NH + hh], W2[hh][ss], r);
        out[(b * S_ + s0 + ss) * COUT + o] = r;
    }
}

extern "C" void kernel_launch(void* const* d_in, const int* in_sizes, int n_in,
                              void* d_out, int out_size, void* d_ws, size_t ws_size,
                              hipStream_t stream) {
    const float* x       = (const float*)d_in[0];
    const float* embed_w = (const float*)d_in[1];
    const float* q_w     = (const float*)d_in[2];
    const float* k_w     = (const float*)d_in[3];
    const float* v_w     = (const float*)d_in[4];
    const float* o_w     = (const float*)d_in[5];
    const float* merge_w = (const float*)d_in[6];
    float* ws  = (float*)d_ws;
    float* out = (float*)d_out;

    k_prep<<<1, 256, 0, stream>>>(embed_w, q_w, k_w, v_w, o_w, ws);
    k_tr<<<B_ * 32, 256, 0, stream>>>(x, ws);
    k_attn<<<64 * 4 * NJ, 256, 0, stream>>>(ws + WS_T, ws + WS_A,
                                            ws + WS_P, ws + WS_P + PSZ);
    k_fin<<<B_ * 64, 256, 0, stream>>>(ws, merge_w, out);
}